// Round 7
// baseline (126.612 us; speedup 1.0000x reference)
//
#include <hip/hip_runtime.h>
#include <cstddef>

// LinOSS-IM: P=256, H=128, B=4, L=4096
#define P_DIM 256
#define H_DIM 128
#define B_SZ 4
#define L_SEQ 4096
#define PC 512                      // 2*P real components (re,im interleaved)
#define M_ROWS (B_SZ * L_SEQ)       // 16384
#define CL 32                       // scan chunk length
#define CLOG 5                      // log2(CL)
#define NC (L_SEQ / CL)             // 128 chunks
#define OUT_BASE (B_SZ * L_SEQ * H_DIM)

#define USE_MFMA 1                  // flip to 0 to restore f32-GEMM baseline

typedef __attribute__((ext_vector_type(8))) short s8v;   // 8 bf16 (4 VGPRs)
typedef __attribute__((ext_vector_type(4))) float f32x4; // MFMA accumulator

// ---- bf16 helpers (manual RNE) --------------------------------------------
__device__ __forceinline__ unsigned short f2bf(float x) {
  unsigned u = __builtin_bit_cast(unsigned, x);
  unsigned r = (u + 0x7FFFu + ((u >> 16) & 1u)) >> 16;
  return (unsigned short)r;
}
__device__ __forceinline__ float bf2f(unsigned short h) {
  return __builtin_bit_cast(float, (unsigned)h << 16);
}
__device__ __forceinline__ void f2hl(float x, short& h, short& l) {
  unsigned short hb = f2bf(x);
  float hf = bf2f(hb);
  unsigned short lb = f2bf(x - hf);
  h = (short)hb; l = (short)lb;
}

// ---------------------------------------------------------------------------
// Scan math: M is REAL (A_diag, step real) => complex recurrence splits into
// independent re/im chains. Thread t = (p, comp), t = p*2 + c matches the
// complex64 interleave.
// ---------------------------------------------------------------------------
__device__ __forceinline__ void make_M(const float* A_diag, const float* step, int p,
                                       float& M11, float& M12, float& M21, float& M22) {
  float Ad = A_diag[p], s = step[p];
  float sig = 1.0f / fmaf(s * s, Ad, 1.0f);   // schur
  M11 = 1.0f - s * s * Ad * sig;
  M12 = -s * Ad * sig;
  M21 = s * sig;
  M22 = sig;
}

#if USE_MFMA
// ---------------------------------------------------------------------------
// K0: prep  Bw[n=(p,c)][h] = step[p]*B[p][h][c]
//     CtH/CtL: B-operand fragments of Ct[k=(p,c)][h] = +/-C[h][p][c], bf16
//     hi/lo, frag layout: idx = ((nt*16+ks)*64+lane)*8+j with
//     n = nt*16+(lane&15), k = ks*32+(lane>>4)*8+j.
// ---------------------------------------------------------------------------
__global__ __launch_bounds__(256) void prep_kernel(const float* __restrict__ Bin,
                                                   const float* __restrict__ Cin,
                                                   const float* __restrict__ step,
                                                   float* __restrict__ Bw,
                                                   short* __restrict__ CtH,
                                                   short* __restrict__ CtL) {
  int idx = blockIdx.x * 256 + threadIdx.x;    // 0..65535
  {
    int kk = idx >> 7, h = idx & 127;
    int p = kk >> 1, c = kk & 1;
    Bw[idx] = step[p] * Bin[(p * H_DIM + h) * 2 + c];
  }
  {
    int j = idx & 7, lane = (idx >> 3) & 63, ks = (idx >> 9) & 15, nt = idx >> 13;
    int h = nt * 16 + (lane & 15);
    int k = ks * 32 + (lane >> 4) * 8 + j;
    // Ct[k][h] = sign * C[h][p][c]; Cin flat: h*512 + k  (k = p*2+c)
    float v = Cin[(size_t)h * PC + k] * ((k & 1) ? -1.0f : 1.0f);
    short hh, ll; f2hl(v, hh, ll);
    CtH[idx] = hh; CtL[idx] = ll;
  }
}

// ---------------------------------------------------------------------------
// K1: NT GEMM, split-bf16 MFMA:  sBu[M][512] = U[M][128] * Bw[512][128]^T
// BM=64, BN=128, KSTEP=64, 256 threads (4 waves, wave tile 32x64).
// x = hi + lo (bf16 each); x*y ~= xh*yh + xh*yl + xl*yh  (lo*lo ~2^-34, drop).
// ---------------------------------------------------------------------------
template<int KTOT, int LDC>
__global__ __launch_bounds__(256) void gemm_nt_mfma(const float* __restrict__ A,
                                                    const float* __restrict__ Bt,
                                                    float* __restrict__ Cout) {
  __shared__ short As_h[64][72], As_l[64][72];     // +8 pad: 144B stride
  __shared__ short Bs_h[128][72], Bs_l[128][72];
  const int t = threadIdx.x;
  const int lane = t & 63;
  const int wid = t >> 6;
  const int wm = (wid & 1) * 32;
  const int wn = (wid >> 1) * 64;
  const int m0 = blockIdx.y * 64;
  const int n0 = blockIdx.x * 128;
  const int lr  = lane & 15;
  const int kb8 = (lane >> 4) * 8;
  const int ar = t >> 4;
  const int ac = (t & 15) * 4;

  f32x4 acc[2][4] = {};

  for (int ks = 0; ks < KTOT / 64; ++ks) {
    const int k0 = ks * 64;
    float4 av[4], bv[8];
#pragma unroll
    for (int j = 0; j < 4; ++j)
      av[j] = *(const float4*)&A[(size_t)(m0 + ar + 16 * j) * KTOT + k0 + ac];
#pragma unroll
    for (int j = 0; j < 8; ++j)
      bv[j] = *(const float4*)&Bt[(size_t)(n0 + ar + 16 * j) * KTOT + k0 + ac];
    __syncthreads();                       // prior step's frag reads done
#pragma unroll
    for (int j = 0; j < 4; ++j) {
      short4 h4, l4;
      f2hl(av[j].x, h4.x, l4.x); f2hl(av[j].y, h4.y, l4.y);
      f2hl(av[j].z, h4.z, l4.z); f2hl(av[j].w, h4.w, l4.w);
      *(short4*)&As_h[ar + 16 * j][ac] = h4;
      *(short4*)&As_l[ar + 16 * j][ac] = l4;
    }
#pragma unroll
    for (int j = 0; j < 8; ++j) {
      short4 h4, l4;
      f2hl(bv[j].x, h4.x, l4.x); f2hl(bv[j].y, h4.y, l4.y);
      f2hl(bv[j].z, h4.z, l4.z); f2hl(bv[j].w, h4.w, l4.w);
      *(short4*)&Bs_h[ar + 16 * j][ac] = h4;
      *(short4*)&Bs_l[ar + 16 * j][ac] = l4;
    }
    __syncthreads();
#pragma unroll
    for (int kb = 0; kb < 2; ++kb) {
      s8v ah[2], al[2], bh[4], bl[4];
#pragma unroll
      for (int ti = 0; ti < 2; ++ti) {
        ah[ti] = *(const s8v*)&As_h[wm + ti * 16 + lr][kb * 32 + kb8];
        al[ti] = *(const s8v*)&As_l[wm + ti * 16 + lr][kb * 32 + kb8];
      }
#pragma unroll
      for (int tj = 0; tj < 4; ++tj) {
        bh[tj] = *(const s8v*)&Bs_h[wn + tj * 16 + lr][kb * 32 + kb8];
        bl[tj] = *(const s8v*)&Bs_l[wn + tj * 16 + lr][kb * 32 + kb8];
      }
#pragma unroll
      for (int ti = 0; ti < 2; ++ti)
#pragma unroll
        for (int tj = 0; tj < 4; ++tj) {
          acc[ti][tj] = __builtin_amdgcn_mfma_f32_16x16x32_bf16(ah[ti], bh[tj], acc[ti][tj], 0, 0, 0);
          acc[ti][tj] = __builtin_amdgcn_mfma_f32_16x16x32_bf16(ah[ti], bl[tj], acc[ti][tj], 0, 0, 0);
          acc[ti][tj] = __builtin_amdgcn_mfma_f32_16x16x32_bf16(al[ti], bh[tj], acc[ti][tj], 0, 0, 0);
        }
    }
  }
  // epilogue: C/D layout col=lane&15, row=(lane>>4)*4+reg  [m89/m91]
  const int rb = (lane >> 4) * 4;
#pragma unroll
  for (int ti = 0; ti < 2; ++ti)
#pragma unroll
    for (int tj = 0; tj < 4; ++tj) {
      const int row = m0 + wm + ti * 16 + rb;
      const int col = n0 + wn + tj * 16 + lr;
#pragma unroll
      for (int r = 0; r < 4; ++r)
        Cout[(size_t)(row + r) * LDC + col] = acc[ti][tj][r];
    }
}

// ---------------------------------------------------------------------------
// K4 (fused): per (b, chunk): scan 32 steps -> ys as TWO bf16 planes (hi/lo)
// in LDS, converted once at production. XOR swizzle col ^= (row&7)<<3.
// Then out[32][128] = ys[32][512] x Ct[512][128] via split-bf16 MFMA with
// B-frags streamed from prepped CtH/CtL (L2-hot). ys never touches HBM.
// ---------------------------------------------------------------------------
__global__ __launch_bounds__(512) void emit_gemm_kernel(const float* __restrict__ A_diag,
                                                        const float* __restrict__ step,
                                                        const float* __restrict__ carryIn,
                                                        const float* __restrict__ sBu,
                                                        const short* __restrict__ CtH,
                                                        const short* __restrict__ CtL,
                                                        float* __restrict__ outp) {
  __shared__ short ys_h[32][512];   // 32KB; col stored as t ^ ((row&7)<<3)
  __shared__ short ys_l[32][512];   // 32KB
  const int t = threadIdx.x;
  const int b = blockIdx.y, ch = blockIdx.x;

  // ---- phase 1: seeded scan of CL=32 steps, one component per thread ----
  {
    const int p = t >> 1;
    float M11, M12, M21, M22;
    make_M(A_diag, step, p, M11, M12, M21, M22);
    size_t o = (((size_t)b * NC + ch) * PC + t) * 2;
    float z = carryIn[o], y = carryIn[o + 1];
    const float* fp = sBu + ((size_t)b * L_SEQ + (size_t)ch * CL) * PC + t;
#pragma unroll 8
    for (int i = 0; i < CL; ++i) {
      float f = fp[(size_t)i * PC];
      float zf = z + f;
      z = fmaf(M11, zf, M12 * y);
      y = fmaf(M21, zf, M22 * y);
      short hh, ll; f2hl(y, hh, ll);
      const int c = t ^ ((i & 7) << 3);
      ys_h[i][c] = hh;
      ys_l[i][c] = ll;
    }
  }
  __syncthreads();

  // ---- phase 2: 8 waves, wave w -> m-tile (w&1), n-tiles (w>>1)*2+{0,1} ----
  const int w = t >> 6, lane = t & 63;
  const int mt = w & 1;
  const int ntb = (w >> 1) * 2;
  const int lr = lane & 15, kb8 = (lane >> 4) * 8;
  const int mrow = mt * 16 + lr;
  const int msw = (mrow & 7) << 3;
  f32x4 acc[2] = {};
  for (int ks = 0; ks < 16; ++ks) {
    const int kc = (ks * 32 + kb8) ^ msw;     // swizzled; (base^msw)+j==(base+j)^msw
    s8v ah = *(const s8v*)&ys_h[mrow][kc];
    s8v al = *(const s8v*)&ys_l[mrow][kc];
#pragma unroll
    for (int q = 0; q < 2; ++q) {
      const int nt = ntb + q;
      size_t fo = (((size_t)nt * 16 + ks) * 64 + lane) * 8;
      s8v bh = *(const s8v*)&CtH[fo];
      s8v bl = *(const s8v*)&CtL[fo];
      acc[q] = __builtin_amdgcn_mfma_f32_16x16x32_bf16(ah, bh, acc[q], 0, 0, 0);
      acc[q] = __builtin_amdgcn_mfma_f32_16x16x32_bf16(al, bh, acc[q], 0, 0, 0);
      acc[q] = __builtin_amdgcn_mfma_f32_16x16x32_bf16(ah, bl, acc[q], 0, 0, 0);
    }
  }
  // epilogue: row=m (time), col=n (h)
  const int rb = (lane >> 4) * 4;
  const size_t rowbase = (size_t)b * L_SEQ + (size_t)ch * CL;
#pragma unroll
  for (int q = 0; q < 2; ++q) {
    const int col = (ntb + q) * 16 + lr;
#pragma unroll
    for (int r = 0; r < 4; ++r) {
      int m = mt * 16 + rb + r;
      outp[(rowbase + m) * H_DIM + col] = acc[q][r];
    }
  }
}
#else
// ---------------------------------------------------------------------------
// f32 fallback path (known-good baseline): prep + 2 f32 GEMMs + scan_emit
// ---------------------------------------------------------------------------
__global__ __launch_bounds__(256) void prep_kernel_f32(const float* __restrict__ Bin,
                                                       const float* __restrict__ Cin,
                                                       const float* __restrict__ step,
                                                       float* __restrict__ Bw,
                                                       float* __restrict__ Ct) {
  int idx = blockIdx.x * 256 + threadIdx.x;
  int kk = idx >> 7, h = idx & 127;
  int p = kk >> 1, c = kk & 1;
  Bw[idx] = step[p] * Bin[(p * H_DIM + h) * 2 + c];
  float cv = Cin[(h * P_DIM + p) * 2 + c];
  Ct[idx] = (c == 0) ? cv : -cv;
}

__global__ __launch_bounds__(256) void gemm_nt_kernel(const float* __restrict__ A,
                                                      const float* __restrict__ Bm,
                                                      float* __restrict__ Cout) {
  __shared__ float As[16][132];
  __shared__ float Bs[16][132];
  const int t = threadIdx.x;
  const int m0 = blockIdx.y * 128;
  const int n0 = blockIdx.x * 128;
  const int tm0 = (t & 15) * 8;
  const int tn0 = (t >> 4) * 8;
  const int row = t >> 2;
  const int kq  = (t & 3) * 4;
  float acc[8][8] = {};
  for (int k0 = 0; k0 < 128; k0 += 16) {
    float4 a0 = *(const float4*)&A[(size_t)(m0 + row) * 128 + k0 + kq];
    float4 a1 = *(const float4*)&A[(size_t)(m0 + row + 64) * 128 + k0 + kq];
    float4 b0 = *(const float4*)&Bm[(size_t)(n0 + row) * 128 + k0 + kq];
    float4 b1 = *(const float4*)&Bm[(size_t)(n0 + row + 64) * 128 + k0 + kq];
    __syncthreads();
    As[kq + 0][row] = a0.x; As[kq + 1][row] = a0.y; As[kq + 2][row] = a0.z; As[kq + 3][row] = a0.w;
    As[kq + 0][row + 64] = a1.x; As[kq + 1][row + 64] = a1.y; As[kq + 2][row + 64] = a1.z; As[kq + 3][row + 64] = a1.w;
    Bs[kq + 0][row] = b0.x; Bs[kq + 1][row] = b0.y; Bs[kq + 2][row] = b0.z; Bs[kq + 3][row] = b0.w;
    Bs[kq + 0][row + 64] = b1.x; Bs[kq + 1][row + 64] = b1.y; Bs[kq + 2][row + 64] = b1.z; Bs[kq + 3][row + 64] = b1.w;
    __syncthreads();
#pragma unroll
    for (int k = 0; k < 16; ++k) {
      float4 a03 = *(const float4*)&As[k][tm0];
      float4 a47 = *(const float4*)&As[k][tm0 + 4];
      float4 b03 = *(const float4*)&Bs[k][tn0];
      float4 b47 = *(const float4*)&Bs[k][tn0 + 4];
      float av[8] = {a03.x, a03.y, a03.z, a03.w, a47.x, a47.y, a47.z, a47.w};
      float bv[8] = {b03.x, b03.y, b03.z, b03.w, b47.x, b47.y, b47.z, b47.w};
#pragma unroll
      for (int i = 0; i < 8; ++i)
#pragma unroll
        for (int j = 0; j < 8; ++j)
          acc[i][j] = fmaf(av[i], bv[j], acc[i][j]);
    }
  }
#pragma unroll
  for (int i = 0; i < 8; ++i) {
    float4 v0 = make_float4(acc[i][0], acc[i][1], acc[i][2], acc[i][3]);
    float4 v1 = make_float4(acc[i][4], acc[i][5], acc[i][6], acc[i][7]);
    *(float4*)&Cout[(size_t)(m0 + tm0 + i) * PC + n0 + tn0] = v0;
    *(float4*)&Cout[(size_t)(m0 + tm0 + i) * PC + n0 + tn0 + 4] = v1;
  }
}

__global__ __launch_bounds__(512) void scan_emit_kernel(const float* __restrict__ A_diag,
                                                        const float* __restrict__ step,
                                                        const float* __restrict__ carryIn,
                                                        float* __restrict__ sBu) {
  const int t = threadIdx.x;
  const int p = t >> 1;
  const int b = blockIdx.y;
  const int ch = blockIdx.x;
  float M11, M12, M21, M22;
  make_M(A_diag, step, p, M11, M12, M21, M22);
  size_t o = (((size_t)b * NC + ch) * PC + t) * 2;
  float z = carryIn[o], y = carryIn[o + 1];
  float* fp = sBu + ((size_t)b * L_SEQ + (size_t)ch * CL) * PC + t;
#pragma unroll 8
  for (int i = 0; i < CL; ++i) {
    float f = fp[(size_t)i * PC];
    float zf = z + f;
    z = fmaf(M11, zf, M12 * y);
    y = fmaf(M21, zf, M22 * y);
    fp[(size_t)i * PC] = y;
  }
}

__global__ __launch_bounds__(256) void gemm_nn_kernel(const float* __restrict__ A,
                                                      const float* __restrict__ Bm,
                                                      float* __restrict__ Cout) {
  __shared__ float As[16][132];
  __shared__ float Bs[16][68];
  const int t = threadIdx.x;
  const int m0 = blockIdx.y * 128;
  const int n0 = blockIdx.x * 64;
  const int tm0 = (t & 15) * 8;
  const int tn0 = (t >> 4) * 4;
  const int row = t >> 2;
  const int kq  = (t & 3) * 4;
  const int bk_row = t >> 4;
  const int bk_c4  = (t & 15) * 4;
  float acc[8][4] = {};
  for (int k0 = 0; k0 < 512; k0 += 16) {
    float4 a0 = *(const float4*)&A[(size_t)(m0 + row) * PC + k0 + kq];
    float4 a1 = *(const float4*)&A[(size_t)(m0 + row + 64) * PC + k0 + kq];
    float4 bv = *(const float4*)&Bm[(size_t)(k0 + bk_row) * H_DIM + n0 + bk_c4];
    __syncthreads();
    As[kq + 0][row] = a0.x; As[kq + 1][row] = a0.y; As[kq + 2][row] = a0.z; As[kq + 3][row] = a0.w;
    As[kq + 0][row + 64] = a1.x; As[kq + 1][row + 64] = a1.y; As[kq + 2][row + 64] = a1.z; As[kq + 3][row + 64] = a1.w;
    *(float4*)&Bs[bk_row][bk_c4] = bv;
    __syncthreads();
#pragma unroll
    for (int k = 0; k < 16; ++k) {
      float4 a03 = *(const float4*)&As[k][tm0];
      float4 a47 = *(const float4*)&As[k][tm0 + 4];
      float4 b03 = *(const float4*)&Bs[k][tn0];
      float av[8] = {a03.x, a03.y, a03.z, a03.w, a47.x, a47.y, a47.z, a47.w};
      float bv4[4] = {b03.x, b03.y, b03.z, b03.w};
#pragma unroll
      for (int i = 0; i < 8; ++i)
#pragma unroll
        for (int j = 0; j < 4; ++j)
          acc[i][j] = fmaf(av[i], bv4[j], acc[i][j]);
    }
  }
#pragma unroll
  for (int i = 0; i < 8; ++i) {
    float4 v = make_float4(acc[i][0], acc[i][1], acc[i][2], acc[i][3]);
    *(float4*)&Cout[(size_t)(m0 + tm0 + i) * H_DIM + n0 + tn0] = v;
  }
}
#endif  // USE_MFMA

// ---------------------------------------------------------------------------
// K2a: chunk-local scan, zero init; store chunk-final (z,y)
// ---------------------------------------------------------------------------
__global__ __launch_bounds__(512) void scan_local_kernel(const float* __restrict__ A_diag,
                                                         const float* __restrict__ step,
                                                         const float* __restrict__ sBu,
                                                         float* __restrict__ carries) {
  const int t = threadIdx.x;
  const int p = t >> 1;
  const int b = blockIdx.y;
  const int ch = blockIdx.x;
  float M11, M12, M21, M22;
  make_M(A_diag, step, p, M11, M12, M21, M22);
  const float* fp = sBu + ((size_t)b * L_SEQ + (size_t)ch * CL) * PC + t;
  float z = 0.f, y = 0.f;
#pragma unroll 8
  for (int i = 0; i < CL; ++i) {
    float f = fp[(size_t)i * PC];
    float zf = z + f;
    z = fmaf(M11, zf, M12 * y);
    y = fmaf(M21, zf, M22 * y);
  }
  size_t o = (((size_t)b * NC + ch) * PC + t) * 2;
  carries[o] = z; carries[o + 1] = y;
}

// ---------------------------------------------------------------------------
// K2b: combine carries across chunks with Mc = M^CL; write carry-ins and the
// final states z_f, y_f into the d_out tail. Tail layout is selected at
// runtime from out_size (complex64 -> float conversion semantics differ):
//   mode 0: interleaved re/im per state   [b*512 + 2p + c]   (out=OUT_BASE+4096, .view)
//   mode 1: REAL part only, planar        [b*256 + p]        (out=OUT_BASE+2048, .astype)
//   mode 2: planar re-plane then im-plane [c*1024 + b*256+p] (out=OUT_BASE+4096, stack ax0)
// ---------------------------------------------------------------------------
__global__ __launch_bounds__(512) void combine_kernel(const float* __restrict__ A_diag,
                                                      const float* __restrict__ step,
                                                      const float* __restrict__ carries,
                                                      float* __restrict__ carryIn,
                                                      float* __restrict__ outp,
                                                      int mode) {
  const int t = threadIdx.x;
  const int p = t >> 1;
  const int b = blockIdx.x;
  float M11, M12, M21, M22;
  make_M(A_diag, step, p, M11, M12, M21, M22);
  float X11 = M11, X12 = M12, X21 = M21, X22 = M22;
#pragma unroll
  for (int i = 0; i < CLOG; ++i) {
    float a = X11 * X11 + X12 * X21;
    float bb = X11 * X12 + X12 * X22;
    float cc = X21 * X11 + X22 * X21;
    float dd = X21 * X12 + X22 * X22;
    X11 = a; X12 = bb; X21 = cc; X22 = dd;
  }
  float z = 0.f, y = 0.f;
#pragma unroll 4
  for (int k = 0; k < NC; ++k) {
    size_t o = (((size_t)b * NC + k) * PC + t) * 2;
    carryIn[o] = z; carryIn[o + 1] = y;
    float sz = carries[o], sy = carries[o + 1];
    float zn = X11 * z + X12 * y + sz;
    float yn = X21 * z + X22 * y + sy;
    z = zn; y = yn;
  }
  const int c = t & 1;
  if (mode == 1) {
    if (c == 0) {                       // real part only, planar [b][p]
      outp[OUT_BASE + (size_t)b * 256 + p] = z;
      outp[OUT_BASE + 1024 + (size_t)b * 256 + p] = y;
    }
  } else if (mode == 2) {               // planar re-plane then im-plane
    outp[OUT_BASE + (size_t)c * 1024 + (size_t)b * 256 + p] = z;
    outp[OUT_BASE + 2048 + (size_t)c * 1024 + (size_t)b * 256 + p] = y;
  } else {                              // interleaved complex64 view
    outp[OUT_BASE + (size_t)b * PC + t] = z;
    outp[OUT_BASE + 2048 + (size_t)b * PC + t] = y;
  }
}

// ---------------------------------------------------------------------------
extern "C" void kernel_launch(void* const* d_in, const int* in_sizes, int n_in,
                              void* d_out, int out_size, void* d_ws, size_t ws_size,
                              hipStream_t stream) {
  const float* A_diag = (const float*)d_in[0];
  const float* Bin    = (const float*)d_in[1];
  const float* Cin    = (const float*)d_in[2];
  const float* U      = (const float*)d_in[3];   // [B,L,H]
  const float* step   = (const float*)d_in[4];
  float* outp = (float*)d_out;
  float* ws = (float*)d_ws;

  // Tail layout: interleaved (.view) already falsified at size OUT_BASE+4096
  // (r6: Output-1 absmax == ref magnitude). Select by out_size:
  int mode;
  if (out_size == OUT_BASE + 2048) mode = 1;        // real-only planar
  else if (out_size == OUT_BASE + 4096) mode = 2;   // planar re/im (2nd try at this size)
  else mode = 0;                                    // fallback: interleaved

  float* Bw      = ws;                       // [512][128] f32
  float* CtA     = Bw + 65536;               // MFMA: CtH+CtL (64K shorts each); f32: Ct[512][128]
  float* sBu     = CtA + 65536;              // [16384][512] f32
  float* carries = sBu + 8388608;            // [4][128][512][2]
  float* carryIn = carries + 524288;
  // total ws use: ~38.3 MB

#if USE_MFMA
  short* CtH = (short*)CtA;
  short* CtL = CtH + 65536;
  prep_kernel<<<256, 256, 0, stream>>>(Bin, Cin, step, Bw, CtH, CtL);
  gemm_nt_mfma<128, 512><<<dim3(4, 256), 256, 0, stream>>>(U, Bw, sBu);
  scan_local_kernel<<<dim3(NC, B_SZ), 512, 0, stream>>>(A_diag, step, sBu, carries);
  combine_kernel<<<B_SZ, 512, 0, stream>>>(A_diag, step, carries, carryIn, outp, mode);
  emit_gemm_kernel<<<dim3(NC, B_SZ), 512, 0, stream>>>(A_diag, step, carryIn, sBu,
                                                       CtH, CtL, outp);
#else
  prep_kernel_f32<<<256, 256, 0, stream>>>(Bin, Cin, step, Bw, CtA);
  gemm_nt_kernel<<<dim3(4, 128), 256, 0, stream>>>(U, Bw, sBu);
  scan_local_kernel<<<dim3(NC, B_SZ), 512, 0, stream>>>(A_diag, step, sBu, carries);
  combine_kernel<<<B_SZ, 512, 0, stream>>>(A_diag, step, carries, carryIn, outp, mode);
  scan_emit_kernel<<<dim3(NC, B_SZ), 512, 0, stream>>>(A_diag, step, carryIn, sBu);
  gemm_nn_kernel<<<dim3(2, 128), 256, 0, stream>>>(sBu, CtA, outp);
#endif
}